// Round 1
// baseline (611.588 us; speedup 1.0000x reference)
//
#include <hip/hip_runtime.h>
#include <math.h>

// ---------------------------------------------------------------------------
// CrossAttnMLP fused implementation for gfx950.
// K0 (weight fp32->bf16 + attention composite Wc=wo@wv + zero stats) ->
// K1 (fused transformer body -> h1_pre + BN1 partial stats) ->
// K2 (BN1 apply + gelu + h2 GEMM + BN2 stats) -> K3 (BN2 apply + gelu + dot).
//
// K1 restructure vs previous version:
//  - attention v_proj/out_proj folded into one 128x128 composite GEMM
//  - LDS 79.9KB -> 52KB  => 3 blocks/CU (12 waves) instead of 2 (8 waves)
//  - x staged in K=64 chunks, issue-early/write-late (T14): 14 barrier
//    intervals instead of 27 for P1/P2, HBM latency hidden under MFMA
//  - both attention GEMMs in a single barrier interval (dual accumulators)
// ---------------------------------------------------------------------------

typedef __attribute__((ext_vector_type(8))) __bf16 bf16x8;
typedef __attribute__((ext_vector_type(8))) short s16x8;
typedef __attribute__((ext_vector_type(4))) float f32x4;

union S8U { s16x8 s; bf16x8 b; };

__device__ __forceinline__ short f2b(float f) {
  union { float f; unsigned u; } v; v.f = f;
  unsigned r = v.u + 0x7fffu + ((v.u >> 16) & 1u);   // RNE
  return (short)(r >> 16);
}
__device__ __forceinline__ float b2f(short s) {
  union { unsigned u; float f; } v; v.u = ((unsigned)(unsigned short)s) << 16;
  return v.f;
}
__device__ __forceinline__ float gelu_f(float x) {
  return 0.5f * x * (1.0f + erff(x * 0.7071067811865475f));
}

// One K=32 MFMA step over a 64-row x (NTS*16)-col tile for one wave.
template<int NTS>
__device__ __forceinline__ void mfma_step(const short* __restrict__ Abuf, int lda, int kkA,
                                          const short* __restrict__ W, int ldw, int kw,
                                          int colbase, int l16, int q,
                                          f32x4 (&acc)[4][NTS]) {
  S8U a[4];
#pragma unroll
  for (int mt = 0; mt < 4; ++mt)
    a[mt].s = *(const s16x8*)(Abuf + (16 * mt + l16) * lda + kkA + 8 * q);
#pragma unroll
  for (int nt = 0; nt < NTS; ++nt) {
    S8U b;
    b.s = *(const s16x8*)(W + (size_t)(colbase + 16 * nt + l16) * ldw + kw + 8 * q);
#pragma unroll
    for (int mt = 0; mt < 4; ++mt)
      acc[mt][nt] = __builtin_amdgcn_mfma_f32_16x16x32_bf16(a[mt].b, b.b, acc[mt][nt], 0, 0, 0);
  }
}

template<int NTS>
__device__ __forceinline__ void zero_acc(f32x4 (&acc)[4][NTS]) {
  f32x4 z = {0.f, 0.f, 0.f, 0.f};
#pragma unroll
  for (int mt = 0; mt < 4; ++mt)
#pragma unroll
    for (int nt = 0; nt < NTS; ++nt) acc[mt][nt] = z;
}

__device__ __forceinline__ void epi_bias_store(f32x4 (&acc)[4][2], const float* __restrict__ bias,
                                               short* dst, int w, int l16, int q, bool do_gelu) {
#pragma unroll
  for (int nt = 0; nt < 2; ++nt) {
    int col = 32 * w + 16 * nt + l16;
    float bb = bias[col];
#pragma unroll
    for (int mt = 0; mt < 4; ++mt)
#pragma unroll
      for (int r = 0; r < 4; ++r) {
        int row = 16 * mt + 4 * q + r;
        float v = acc[mt][nt][r] + bb;
        if (do_gelu) v = gelu_f(v);
        dst[row * 136 + col] = f2b(v);
      }
  }
}

// Epilogue: acc += bias + residual(resbuf), LayerNorm over 128 cols, write dst.
__device__ __forceinline__ void epi_res_ln(f32x4 (&acc)[4][2], const float* __restrict__ bias,
                                           const short* resbuf,
                                           const float* __restrict__ g, const float* __restrict__ bta,
                                           short* dst, float (*lnp)[4][2], float (*murs)[2],
                                           int w, int l16, int q, int tid) {
#pragma unroll
  for (int nt = 0; nt < 2; ++nt) {
    int col = 32 * w + 16 * nt + l16;
    float bb = bias[col];
#pragma unroll
    for (int mt = 0; mt < 4; ++mt)
#pragma unroll
      for (int r = 0; r < 4; ++r) {
        int row = 16 * mt + 4 * q + r;
        acc[mt][nt][r] += bb + b2f(resbuf[row * 136 + col]);
      }
  }
#pragma unroll
  for (int mt = 0; mt < 4; ++mt) {
#pragma unroll
    for (int r = 0; r < 4; ++r) {
      float v0 = acc[mt][0][r], v1 = acc[mt][1][r];
      float s = v0 + v1;
      float sq = v0 * v0 + v1 * v1;
#pragma unroll
      for (int off = 1; off < 16; off <<= 1) {
        s += __shfl_xor(s, off);
        sq += __shfl_xor(sq, off);
      }
      if (l16 == 0) {
        int row = 16 * mt + 4 * q + r;
        lnp[row][w][0] = s;
        lnp[row][w][1] = sq;
      }
    }
  }
  __syncthreads();
  if (tid < 64) {
    float s = lnp[tid][0][0] + lnp[tid][1][0] + lnp[tid][2][0] + lnp[tid][3][0];
    float sq = lnp[tid][0][1] + lnp[tid][1][1] + lnp[tid][2][1] + lnp[tid][3][1];
    float mu = s * (1.0f / 128.0f);
    float var = sq * (1.0f / 128.0f) - mu * mu;
    murs[tid][0] = mu;
    murs[tid][1] = rsqrtf(var + 1e-5f);
  }
  __syncthreads();
#pragma unroll
  for (int nt = 0; nt < 2; ++nt) {
    int col = 32 * w + 16 * nt + l16;
    float gg = g[col], b2 = bta[col];
#pragma unroll
    for (int mt = 0; mt < 4; ++mt)
#pragma unroll
      for (int r = 0; r < 4; ++r) {
        int row = 16 * mt + 4 * q + r;
        float v = (acc[mt][nt][r] - murs[row][0]) * murs[row][1] * gg + b2;
        dst[row * 136 + col] = f2b(v);
      }
  }
}

// FFN block: act = LN(act + W2 @ gelu(W1 @ act + b1) + b2).
// H overlays the LN scratch region, so a trailing barrier protects murs/lnp
// from the next phase's H writes.
__device__ __forceinline__ void ffn_block(const short* __restrict__ w1, const short* __restrict__ w2,
                                          const float* __restrict__ b1, const float* __restrict__ b2,
                                          const float* __restrict__ g, const float* __restrict__ bta,
                                          short* act, short* H,
                                          float (*lnp)[4][2], float (*murs)[2],
                                          int w, int l16, int q, int tid) {
  f32x4 acc2[4][2];
  zero_acc(acc2);
  for (int c = 0; c < 4; ++c) {
    f32x4 acch[4][2];
    zero_acc(acch);
#pragma unroll
    for (int kk = 0; kk < 4; ++kk)
      mfma_step<2>(act, 136, 32 * kk, w1, 128, 32 * kk, c * 128 + 32 * w, l16, q, acch);
#pragma unroll
    for (int nt = 0; nt < 2; ++nt) {
      int lcol = 32 * w + 16 * nt + l16;
      float bb = b1[c * 128 + lcol];
#pragma unroll
      for (int mt = 0; mt < 4; ++mt)
#pragma unroll
        for (int r = 0; r < 4; ++r)
          H[(16 * mt + 4 * q + r) * 136 + lcol] = f2b(gelu_f(acch[mt][nt][r] + bb));
    }
    __syncthreads();
#pragma unroll
    for (int kk = 0; kk < 4; ++kk)
      mfma_step<2>(H, 136, 32 * kk, w2, 512, c * 128 + 32 * kk, 32 * w, l16, q, acc2);
    __syncthreads();
  }
  epi_res_ln(acc2, b2, act, g, bta, act, lnp, murs, w, l16, q, tid);
  __syncthreads();   // protect lnp/murs (inside H region) from next H writes
}

// ---------------------------------------------------------------------------
struct K1Args {
  const float* x;
  const short *wpep, *wtcr, *wcp, *wct, *w1p, *w2p, *w1t, *w2t, *wh1;
  const float *bpep, *btcr, *bcp, *bct;
  const float *g1p, *e1p, *g2p, *e2p, *g1t, *e1t, *g2t, *e2t;
  const float *b1p, *b2p, *b1t, *b2t, *bh1;
  float *sum1, *sq1;
  short* h1;
};

__global__ __launch_bounds__(256, 3) void k1_main(K1Args A) {
  // LDS: U,V 64x136 bf16; R = 2x(64x72) staging dbuf, overlaid with FFN H
  // (64x136) and LN scratch (last 2560 B).  Total 53248 B -> 3 blocks/CU.
  __shared__ __align__(16) short smem[2 * 64 * 136 + 2 * 64 * 72];
  short* U = smem;
  short* V = U + 64 * 136;
  short* Rst = V + 64 * 136;
  short* R0 = Rst;
  short* R1 = Rst + 64 * 72;
  short* Hb = Rst;                                        // FFN temp
  float (*lnp)[4][2] = (float (*)[4][2])(void*)(Rst + 7936);   // 2048 B
  float (*murs)[2] = (float (*)[2])(void*)(Rst + 8960);        // 512 B

  const int tid = threadIdx.x;
  const int w = tid >> 6;
  const int lane = tid & 63;
  const int l16 = lane & 15;
  const int q = lane >> 4;
  const size_t row0 = (size_t)blockIdx.x * 64;

  const int r_st = tid >> 2;
  const float* xrow = A.x + (row0 + r_st) * 864;

  float4 pf0, pf1, pf2, pf3;
  auto issue64 = [&](int kb) {
    const float* p = xrow + kb + (tid & 3) * 16;
    pf0 = *(const float4*)(p);
    pf1 = *(const float4*)(p + 4);
    pf2 = *(const float4*)(p + 8);
    pf3 = *(const float4*)(p + 12);
  };
  auto write64 = [&](short* Sb) {
    int c = (tid & 3) * 16;
    s16x8 o0, o1;
    o0[0] = f2b(pf0.x); o0[1] = f2b(pf0.y); o0[2] = f2b(pf0.z); o0[3] = f2b(pf0.w);
    o0[4] = f2b(pf1.x); o0[5] = f2b(pf1.y); o0[6] = f2b(pf1.z); o0[7] = f2b(pf1.w);
    o1[0] = f2b(pf2.x); o1[1] = f2b(pf2.y); o1[2] = f2b(pf2.z); o1[3] = f2b(pf2.w);
    o1[4] = f2b(pf3.x); o1[5] = f2b(pf3.y); o1[6] = f2b(pf3.z); o1[7] = f2b(pf3.w);
    *(s16x8*)(Sb + r_st * 72 + c) = o0;
    *(s16x8*)(Sb + r_st * 72 + c + 8) = o1;
  };
  auto issue32 = [&](int kb) {
    const float* p = xrow + kb + (tid & 3) * 8;
    pf0 = *(const float4*)(p);
    pf1 = *(const float4*)(p + 4);
  };
  auto write32 = [&](short* Sb) {
    int c = (tid & 3) * 8;
    s16x8 o0;
    o0[0] = f2b(pf0.x); o0[1] = f2b(pf0.y); o0[2] = f2b(pf0.z); o0[3] = f2b(pf0.w);
    o0[4] = f2b(pf1.x); o0[5] = f2b(pf1.y); o0[6] = f2b(pf1.z); o0[7] = f2b(pf1.w);
    *(s16x8*)(Sb + r_st * 72 + c) = o0;
  };

  f32x4 accP[4][2], accT[4][2];
  zero_acc(accP); zero_acc(accT);

  // P1+P2 unified pipeline: 14 K=64 chunks over x cols [64t, 64t+64)
  // (chunks 0..5 -> pep/wpep, 6..12 -> tcr/wtcr, 13 -> K=32 tail).
  issue64(0); write64(R0);
  __syncthreads();
  for (int t = 0; t < 14; ++t) {
    short* cur = (t & 1) ? R1 : R0;
    short* nxt = (t & 1) ? R0 : R1;
    if (t < 13) { if (t == 12) issue32(832); else issue64(64 * (t + 1)); }
    if (t < 6) {
      mfma_step<2>(cur, 72, 0,  A.wpep, 384, 64 * t,      32 * w, l16, q, accP);
      mfma_step<2>(cur, 72, 32, A.wpep, 384, 64 * t + 32, 32 * w, l16, q, accP);
    } else if (t < 13) {
      mfma_step<2>(cur, 72, 0,  A.wtcr, 480, 64 * (t - 6),      32 * w, l16, q, accT);
      mfma_step<2>(cur, 72, 32, A.wtcr, 480, 64 * (t - 6) + 32, 32 * w, l16, q, accT);
    } else {
      mfma_step<2>(cur, 72, 0,  A.wtcr, 480, 448, 32 * w, l16, q, accT);
    }
    if (t < 13) { if (t == 12) write32(nxt); else write64(nxt); }
    __syncthreads();
  }
  epi_bias_store(accP, A.bpep, U, w, l16, q, false);   // U = pep
  epi_bias_store(accT, A.btcr, V, w, l16, q, false);   // V = tcr
  __syncthreads();

  // Attention (composited, seq_len=1): pa-pre = tcr @ Wcp^T, ta-pre = pep @ Wct^T.
  // Both GEMMs before either LN epilogue overwrites U/V.
  zero_acc(accP); zero_acc(accT);
#pragma unroll
  for (int kk = 0; kk < 4; ++kk)
    mfma_step<2>(V, 136, 32 * kk, A.wcp, 128, 32 * kk, 32 * w, l16, q, accP);
#pragma unroll
  for (int kk = 0; kk < 4; ++kk)
    mfma_step<2>(U, 136, 32 * kk, A.wct, 128, 32 * kk, 32 * w, l16, q, accT);
  epi_res_ln(accP, A.bcp, U, A.g1p, A.e1p, U, lnp, murs, w, l16, q, tid);
  epi_res_ln(accT, A.bct, V, A.g1t, A.e1t, V, lnp, murs, w, l16, q, tid);
  __syncthreads();   // murs reads done before FFN's H writes hit the overlay

  ffn_block(A.w1p, A.w2p, A.b1p, A.b2p, A.g2p, A.e2p, U, Hb, lnp, murs, w, l16, q, tid);
  ffn_block(A.w1t, A.w2t, A.b1t, A.b2t, A.g2t, A.e2t, V, Hb, lnp, murs, w, l16, q, tid);

  // P9: h1_pre = [pa|ta] @ w_h1^T + b_h1 ; BN1 partial stats ; store bf16
  zero_acc(accP);
#pragma unroll
  for (int s = 0; s < 8; ++s)
    mfma_step<2>((s < 4) ? U : V, 136, 32 * (s & 3), A.wh1, 256, 32 * s, 32 * w, l16, q, accP);
#pragma unroll
  for (int nt = 0; nt < 2; ++nt) {
    int col = 32 * w + 16 * nt + l16;
    float bb = A.bh1[col];
    float s = 0.f, sq = 0.f;
#pragma unroll
    for (int mt = 0; mt < 4; ++mt)
#pragma unroll
      for (int r = 0; r < 4; ++r) {
        float v = accP[mt][nt][r] + bb;
        s += v; sq += v * v;
        A.h1[(row0 + 16 * mt + 4 * q + r) * 128 + col] = f2b(v);
      }
    s += __shfl_xor(s, 16); sq += __shfl_xor(sq, 16);
    s += __shfl_xor(s, 32); sq += __shfl_xor(sq, 32);
    if (q == 0) {
      atomicAdd(&A.sum1[col], s);
      atomicAdd(&A.sq1[col], sq);
    }
  }
}

// ---------------------------------------------------------------------------
struct K2Args {
  const short* h1;
  const short* wh2;
  const float *bh2, *bn1g, *bn1b;
  const float *sum1, *sq1;
  float *sum2, *sq2;
  short* h2;
};

__global__ __launch_bounds__(256) void k2_main(K2Args A) {
  __shared__ __align__(16) short S2[64 * 136];
  __shared__ float s1[128], t1[128];
  const int tid = threadIdx.x;
  const int w = tid >> 6, lane = tid & 63, l16 = lane & 15, q = lane >> 4;
  const size_t row0 = (size_t)blockIdx.x * 64;

  if (tid < 128) {
    float su = A.sum1[tid], sq = A.sq1[tid];
    float mu = su * (1.0f / 65536.0f);
    float var = sq * (1.0f / 65536.0f) - mu * mu;
    float sc = A.bn1g[tid] * rsqrtf(var + 1e-5f);
    s1[tid] = sc;
    t1[tid] = A.bn1b[tid] - mu * sc;
  }
  __syncthreads();
  {
    int r = tid >> 2;
#pragma unroll
    for (int j = 0; j < 4; ++j) {
      int c = (tid & 3) * 32 + j * 8;
      s16x8 hv = *(const s16x8*)(A.h1 + (row0 + r) * 128 + c);
      s16x8 o;
#pragma unroll
      for (int i = 0; i < 8; ++i) {
        float f = b2f(hv[i]);
        f = gelu_f(f * s1[c + i] + t1[c + i]);
        o[i] = f2b(f);
      }
      *(s16x8*)(S2 + r * 136 + c) = o;
    }
  }
  __syncthreads();
  f32x4 acc[4][1];
  zero_acc(acc);
#pragma unroll
  for (int kk = 0; kk < 4; ++kk)
    mfma_step<1>(S2, 136, 32 * kk, A.wh2, 128, 32 * kk, 16 * w, l16, q, acc);
  int col = 16 * w + l16;
  float bb = A.bh2[col];
  float s = 0.f, sq = 0.f;
#pragma unroll
  for (int mt = 0; mt < 4; ++mt)
#pragma unroll
    for (int r = 0; r < 4; ++r) {
      float v = acc[mt][0][r] + bb;
      s += v; sq += v * v;
      A.h2[(row0 + 16 * mt + 4 * q + r) * 64 + col] = f2b(v);
    }
  s += __shfl_xor(s, 16); sq += __shfl_xor(sq, 16);
  s += __shfl_xor(s, 32); sq += __shfl_xor(sq, 32);
  if (q == 0) {
    atomicAdd(&A.sum2[col], s);
    atomicAdd(&A.sq2[col], sq);
  }
}

// ---------------------------------------------------------------------------
struct K3Args {
  const short* h2;
  const float *bn2g, *bn2b;
  const float *sum2, *sq2;
  const float *wout, *bout;
  float* out;
};

__global__ __launch_bounds__(256) void k3_main(K3Args A) {
  __shared__ float s2[64], t2[64], wo[64];
  const int tid = threadIdx.x;
  if (tid < 64) {
    float su = A.sum2[tid], sq = A.sq2[tid];
    float mu = su * (1.0f / 65536.0f);
    float var = sq * (1.0f / 65536.0f) - mu * mu;
    float sc = A.bn2g[tid] * rsqrtf(var + 1e-5f);
    s2[tid] = sc;
    t2[tid] = A.bn2b[tid] - mu * sc;
    wo[tid] = A.wout[tid];
  }
  __syncthreads();
  size_t row = (size_t)blockIdx.x * 32 + (tid >> 3);
  int c0 = (tid & 7) * 8;
  s16x8 hv = *(const s16x8*)(A.h2 + row * 64 + c0);
  float s = 0.f;
#pragma unroll
  for (int i = 0; i < 8; ++i) {
    float f = b2f(hv[i]);
    f = gelu_f(f * s2[c0 + i] + t2[c0 + i]);
    s += f * wo[c0 + i];
  }
  s += __shfl_xor(s, 1); s += __shfl_xor(s, 2); s += __shfl_xor(s, 4);
  if ((tid & 7) == 0) A.out[row] = s + A.bout[0];
}

// ---------------------------------------------------------------------------
struct CvtArgs {
  const float* src[8];
  short* dst;
  float* stats;
  // attention composite fusion inputs/outputs
  const float *wv[2], *wo[2], *bv[2], *bo[2];
  short* wc[2];
  float* bc[2];
};

// Blocks 0..403: fp32->bf16 convert (wv/wo regions skipped: the composite
// replaces them).  Blocks 404..435: Wc = wo@wv (bf16 out) and bc = wo@bv+bo.
__global__ __launch_bounds__(256) void k0_setup(CvtArgs A) {
  int b = blockIdx.x;
  const int tid = threadIdx.x;
  if (b >= 404) {
    int b2 = b - 404, pair = b2 >> 4, part = b2 & 15;
    const float* wv = A.wv[pair];
    const float* wo = A.wo[pair];
#pragma unroll
    for (int i = 0; i < 4; ++i) {
      int idx = part * 1024 + i * 256 + tid;
      int o = idx >> 7, k = idx & 127;
      const float* worow = wo + o * 128;
      float acc = 0.f;
#pragma unroll 4
      for (int j = 0; j < 128; ++j) acc += worow[j] * wv[j * 128 + k];
      A.wc[pair][idx] = f2b(acc);
    }
    if (part == 0 && tid < 128) {
      const float* bvp = A.bv[pair];
      float acc = A.bo[pair][tid];
      for (int j = 0; j < 128; ++j) acc += wo[tid * 128 + j] * bvp[j];
      A.bc[pair][tid] = acc;
    }
    return;
  }
  // segment starts in dst element coordinates (gap [110592,176128) skipped)
  const int st[8] = {0, 49152, 176128, 241664, 307200, 372736, 438272, 471040};
  if (b == 0) {
    A.stats[tid] = 0.0f;
    if (tid < 128) A.stats[256 + tid] = 0.0f;
  }
  int dstbase = b * 1024 + ((b >= 108) ? 65536 : 0);
  int seg = 0;
#pragma unroll
  for (int t = 1; t < 8; ++t) seg += (dstbase >= st[t]) ? 1 : 0;
  const float* s = A.src[seg];
  int loc = dstbase - st[seg] + tid * 4;
  float4 f = *(const float4*)(s + loc);
  int di = dstbase + tid * 4;
  A.dst[di + 0] = f2b(f.x);
  A.dst[di + 1] = f2b(f.y);
  A.dst[di + 2] = f2b(f.z);
  A.dst[di + 3] = f2b(f.w);
}

// ---------------------------------------------------------------------------
extern "C" void kernel_launch(void* const* d_in, const int* in_sizes, int n_in,
                              void* d_out, int out_size, void* d_ws, size_t ws_size,
                              hipStream_t stream) {
  (void)in_sizes; (void)n_in; (void)out_size; (void)ws_size;
  const float* x = (const float*)d_in[0];
  char* ws = (char*)d_ws;
  short* wb = (short*)ws;
  // bf16 weight segment offsets (elements). O_WCP/O_WCT hold the attention
  // composites; composite biases (fp32) live in the old wo_p2t region.
  enum { O_PEP = 0, O_TCR = 49152, O_WCP = 110592, O_BCF = 126976,
         O_WCT = 143360, O_W1P = 176128, O_W2P = 241664,
         O_W1T = 307200, O_W2T = 372736, O_H1 = 438272, O_H2 = 471040 };
  float* stats = (float*)(ws + 958464);           // 384 floats
  short* h1_pre = (short*)(ws + 960000);          // 65536*128 bf16
  short* h2_pre = (short*)(ws + 17737216);        // 65536*64 bf16
  float* bcomp = (float*)(ws + (size_t)O_BCF * 2);  // 256 floats

  CvtArgs ca;
  ca.src[0] = (const float*)d_in[1];   // w_pep
  ca.src[1] = (const float*)d_in[3];   // w_tcr
  ca.src[2] = (const float*)d_in[21];  // ffn_w1p
  ca.src[3] = (const float*)d_in[23];  // ffn_w2p
  ca.src[4] = (const float*)d_in[25];  // ffn_w1t
  ca.src[5] = (const float*)d_in[27];  // ffn_w2t
  ca.src[6] = (const float*)d_in[29];  // w_h1
  ca.src[7] = (const float*)d_in[33];  // w_h2
  ca.dst = wb;
  ca.stats = stats;
  ca.wv[0] = (const float*)d_in[5];   ca.bv[0] = (const float*)d_in[6];
  ca.wo[0] = (const float*)d_in[7];   ca.bo[0] = (const float*)d_in[8];
  ca.wv[1] = (const float*)d_in[9];   ca.bv[1] = (const float*)d_in[10];
  ca.wo[1] = (const float*)d_in[11];  ca.bo[1] = (const float*)d_in[12];
  ca.wc[0] = wb + O_WCP;  ca.wc[1] = wb + O_WCT;
  ca.bc[0] = bcomp;       ca.bc[1] = bcomp + 128;
  k0_setup<<<436, 256, 0, stream>>>(ca);

  K1Args a1;
  a1.x = x;
  a1.wpep = wb + O_PEP;  a1.wtcr = wb + O_TCR;
  a1.wcp = wb + O_WCP;   a1.wct = wb + O_WCT;
  a1.w1p = wb + O_W1P;   a1.w2p = wb + O_W2P;
  a1.w1t = wb + O_W1T;   a1.w2t = wb + O_W2T;
  a1.wh1 = wb + O_H1;
  a1.bpep = (const float*)d_in[2];
  a1.btcr = (const float*)d_in[4];
  a1.bcp = bcomp;
  a1.bct = bcomp + 128;
  a1.g1p = (const float*)d_in[13];  a1.e1p = (const float*)d_in[14];
  a1.g2p = (const float*)d_in[15];  a1.e2p = (const float*)d_in[16];
  a1.g1t = (const float*)d_in[17];  a1.e1t = (const float*)d_in[18];
  a1.g2t = (const float*)d_in[19];  a1.e2t = (const float*)d_in[20];
  a1.b1p = (const float*)d_in[22];
  a1.b2p = (const float*)d_in[24];
  a1.b1t = (const float*)d_in[26];
  a1.b2t = (const float*)d_in[28];
  a1.bh1 = (const float*)d_in[30];
  a1.sum1 = stats;
  a1.sq1 = stats + 128;
  a1.h1 = h1_pre;
  k1_main<<<1024, 256, 0, stream>>>(a1);

  K2Args a2;
  a2.h1 = h1_pre;
  a2.wh2 = wb + O_H2;
  a2.bh2 = (const float*)d_in[34];
  a2.bn1g = (const float*)d_in[31];
  a2.bn1b = (const float*)d_in[32];
  a2.sum1 = stats;
  a2.sq1 = stats + 128;
  a2.sum2 = stats + 256;
  a2.sq2 = stats + 320;
  a2.h2 = h2_pre;
  k2_main<<<1024, 256, 0, stream>>>(a2);

  K3Args a3;
  a3.h2 = h2_pre;
  a3.bn2g = (const float*)d_in[35];
  a3.bn2b = (const float*)d_in[36];
  a3.sum2 = stats + 256;
  a3.sq2 = stats + 320;
  a3.wout = (const float*)d_in[37];
  a3.bout = (const float*)d_in[38];
  a3.out = (float*)d_out;
  k3_main<<<2048, 256, 0, stream>>>(a3);
}

// Round 4
// 568.806 us; speedup vs baseline: 1.0752x; 1.0752x over previous
//
#include <hip/hip_runtime.h>
#include <hip/hip_bf16.h>
#include <math.h>

// ---------------------------------------------------------------------------
// CrossAttnMLP fused implementation for gfx950.
// K0 (weight fp32->bf16 + attention composite Wc=wo@wv + zero stats) ->
// K1 (fused transformer body -> h1_pre + BN1 partial stats) ->
// K2 (BN1 apply + gelu + h2 GEMM + BN2 stats) -> K3 (BN2 apply + gelu + dot).
//
// R2 changes (VALU diet; no sync-structure change):
//  - f2b: manual RNE bit-twiddle (5 VALU ops) -> native f32->bf16 cast (1 op)
//  - gelu: erff-based exact (~25-40 VALU ops, divergent ocml branches) ->
//    sigmoid-form tanh approx (~8 ops, max dev 4e-4 << bf16 quant step)
// ---------------------------------------------------------------------------

typedef __attribute__((ext_vector_type(8))) __bf16 bf16x8;
typedef __attribute__((ext_vector_type(8))) short s16x8;
typedef __attribute__((ext_vector_type(4))) float f32x4;

union S8U { s16x8 s; bf16x8 b; };

__device__ __forceinline__ short f2b(float f) {
  return __builtin_bit_cast(short, (__bf16)f);   // native RNE cvt on gfx950
}
__device__ __forceinline__ float b2f(short s) {
  union { unsigned u; float f; } v; v.u = ((unsigned)(unsigned short)s) << 16;
  return v.f;
}
// gelu(x) = 0.5x(1+tanh(c(x+0.044715x^3))) = x * sigmoid(2c(x+0.044715x^3)).
// Max |err| vs exact erf-gelu ~4e-4, below bf16 quantization of intermediates.
__device__ __forceinline__ float gelu_f(float x) {
  float u = x * __builtin_fmaf(0.035677408136f, x * x, 0.7978845608028654f);
  float e = __expf(-2.0f * u);
  return x * __builtin_amdgcn_rcpf(1.0f + e);
}

// One K=32 MFMA step over a 64-row x (NTS*16)-col tile for one wave.
template<int NTS>
__device__ __forceinline__ void mfma_step(const short* __restrict__ Abuf, int lda, int kkA,
                                          const short* __restrict__ W, int ldw, int kw,
                                          int colbase, int l16, int q,
                                          f32x4 (&acc)[4][NTS]) {
  S8U a[4];
#pragma unroll
  for (int mt = 0; mt < 4; ++mt)
    a[mt].s = *(const s16x8*)(Abuf + (16 * mt + l16) * lda + kkA + 8 * q);
#pragma unroll
  for (int nt = 0; nt < NTS; ++nt) {
    S8U b;
    b.s = *(const s16x8*)(W + (size_t)(colbase + 16 * nt + l16) * ldw + kw + 8 * q);
#pragma unroll
    for (int mt = 0; mt < 4; ++mt)
      acc[mt][nt] = __builtin_amdgcn_mfma_f32_16x16x32_bf16(a[mt].b, b.b, acc[mt][nt], 0, 0, 0);
  }
}

template<int NTS>
__device__ __forceinline__ void zero_acc(f32x4 (&acc)[4][NTS]) {
  f32x4 z = {0.f, 0.f, 0.f, 0.f};
#pragma unroll
  for (int mt = 0; mt < 4; ++mt)
#pragma unroll
    for (int nt = 0; nt < NTS; ++nt) acc[mt][nt] = z;
}

__device__ __forceinline__ void epi_bias_store(f32x4 (&acc)[4][2], const float* __restrict__ bias,
                                               short* dst, int w, int l16, int q, bool do_gelu) {
#pragma unroll
  for (int nt = 0; nt < 2; ++nt) {
    int col = 32 * w + 16 * nt + l16;
    float bb = bias[col];
#pragma unroll
    for (int mt = 0; mt < 4; ++mt)
#pragma unroll
      for (int r = 0; r < 4; ++r) {
        int row = 16 * mt + 4 * q + r;
        float v = acc[mt][nt][r] + bb;
        if (do_gelu) v = gelu_f(v);
        dst[row * 136 + col] = f2b(v);
      }
  }
}

// Epilogue: acc += bias + residual(resbuf), LayerNorm over 128 cols, write dst.
__device__ __forceinline__ void epi_res_ln(f32x4 (&acc)[4][2], const float* __restrict__ bias,
                                           const short* resbuf,
                                           const float* __restrict__ g, const float* __restrict__ bta,
                                           short* dst, float (*lnp)[4][2], float (*murs)[2],
                                           int w, int l16, int q, int tid) {
#pragma unroll
  for (int nt = 0; nt < 2; ++nt) {
    int col = 32 * w + 16 * nt + l16;
    float bb = bias[col];
#pragma unroll
    for (int mt = 0; mt < 4; ++mt)
#pragma unroll
      for (int r = 0; r < 4; ++r) {
        int row = 16 * mt + 4 * q + r;
        acc[mt][nt][r] += bb + b2f(resbuf[row * 136 + col]);
      }
  }
#pragma unroll
  for (int mt = 0; mt < 4; ++mt) {
#pragma unroll
    for (int r = 0; r < 4; ++r) {
      float v0 = acc[mt][0][r], v1 = acc[mt][1][r];
      float s = v0 + v1;
      float sq = v0 * v0 + v1 * v1;
#pragma unroll
      for (int off = 1; off < 16; off <<= 1) {
        s += __shfl_xor(s, off);
        sq += __shfl_xor(sq, off);
      }
      if (l16 == 0) {
        int row = 16 * mt + 4 * q + r;
        lnp[row][w][0] = s;
        lnp[row][w][1] = sq;
      }
    }
  }
  __syncthreads();
  if (tid < 64) {
    float s = lnp[tid][0][0] + lnp[tid][1][0] + lnp[tid][2][0] + lnp[tid][3][0];
    float sq = lnp[tid][0][1] + lnp[tid][1][1] + lnp[tid][2][1] + lnp[tid][3][1];
    float mu = s * (1.0f / 128.0f);
    float var = sq * (1.0f / 128.0f) - mu * mu;
    murs[tid][0] = mu;
    murs[tid][1] = rsqrtf(var + 1e-5f);
  }
  __syncthreads();
#pragma unroll
  for (int nt = 0; nt < 2; ++nt) {
    int col = 32 * w + 16 * nt + l16;
    float gg = g[col], b2 = bta[col];
#pragma unroll
    for (int mt = 0; mt < 4; ++mt)
#pragma unroll
      for (int r = 0; r < 4; ++r) {
        int row = 16 * mt + 4 * q + r;
        float v = (acc[mt][nt][r] - murs[row][0]) * murs[row][1] * gg + b2;
        dst[row * 136 + col] = f2b(v);
      }
  }
}

// FFN block: act = LN(act + W2 @ gelu(W1 @ act + b1) + b2).
// H overlays the LN scratch region, so a trailing barrier protects murs/lnp
// from the next phase's H writes.
__device__ __forceinline__ void ffn_block(const short* __restrict__ w1, const short* __restrict__ w2,
                                          const float* __restrict__ b1, const float* __restrict__ b2,
                                          const float* __restrict__ g, const float* __restrict__ bta,
                                          short* act, short* H,
                                          float (*lnp)[4][2], float (*murs)[2],
                                          int w, int l16, int q, int tid) {
  f32x4 acc2[4][2];
  zero_acc(acc2);
  for (int c = 0; c < 4; ++c) {
    f32x4 acch[4][2];
    zero_acc(acch);
#pragma unroll
    for (int kk = 0; kk < 4; ++kk)
      mfma_step<2>(act, 136, 32 * kk, w1, 128, 32 * kk, c * 128 + 32 * w, l16, q, acch);
#pragma unroll
    for (int nt = 0; nt < 2; ++nt) {
      int lcol = 32 * w + 16 * nt + l16;
      float bb = b1[c * 128 + lcol];
#pragma unroll
      for (int mt = 0; mt < 4; ++mt)
#pragma unroll
        for (int r = 0; r < 4; ++r)
          H[(16 * mt + 4 * q + r) * 136 + lcol] = f2b(gelu_f(acch[mt][nt][r] + bb));
    }
    __syncthreads();
#pragma unroll
    for (int kk = 0; kk < 4; ++kk)
      mfma_step<2>(H, 136, 32 * kk, w2, 512, c * 128 + 32 * kk, 32 * w, l16, q, acc2);
    __syncthreads();
  }
  epi_res_ln(acc2, b2, act, g, bta, act, lnp, murs, w, l16, q, tid);
  __syncthreads();   // protect lnp/murs (inside H region) from next H writes
}

// ---------------------------------------------------------------------------
struct K1Args {
  const float* x;
  const short *wpep, *wtcr, *wcp, *wct, *w1p, *w2p, *w1t, *w2t, *wh1;
  const float *bpep, *btcr, *bcp, *bct;
  const float *g1p, *e1p, *g2p, *e2p, *g1t, *e1t, *g2t, *e2t;
  const float *b1p, *b2p, *b1t, *b2t, *bh1;
  float *sum1, *sq1;
  short* h1;
};

__global__ __launch_bounds__(256, 3) void k1_main(K1Args A) {
  // LDS: U,V 64x136 bf16; R = 2x(64x72) staging dbuf, overlaid with FFN H
  // (64x136) and LN scratch (last 2560 B).  Total 53248 B -> 3 blocks/CU.
  __shared__ __align__(16) short smem[2 * 64 * 136 + 2 * 64 * 72];
  short* U = smem;
  short* V = U + 64 * 136;
  short* Rst = V + 64 * 136;
  short* R0 = Rst;
  short* R1 = Rst + 64 * 72;
  short* Hb = Rst;                                        // FFN temp
  float (*lnp)[4][2] = (float (*)[4][2])(void*)(Rst + 7936);   // 2048 B
  float (*murs)[2] = (float (*)[2])(void*)(Rst + 8960);        // 512 B

  const int tid = threadIdx.x;
  const int w = tid >> 6;
  const int lane = tid & 63;
  const int l16 = lane & 15;
  const int q = lane >> 4;
  const size_t row0 = (size_t)blockIdx.x * 64;

  const int r_st = tid >> 2;
  const float* xrow = A.x + (row0 + r_st) * 864;

  float4 pf0, pf1, pf2, pf3;
  auto issue64 = [&](int kb) {
    const float* p = xrow + kb + (tid & 3) * 16;
    pf0 = *(const float4*)(p);
    pf1 = *(const float4*)(p + 4);
    pf2 = *(const float4*)(p + 8);
    pf3 = *(const float4*)(p + 12);
  };
  auto write64 = [&](short* Sb) {
    int c = (tid & 3) * 16;
    s16x8 o0, o1;
    o0[0] = f2b(pf0.x); o0[1] = f2b(pf0.y); o0[2] = f2b(pf0.z); o0[3] = f2b(pf0.w);
    o0[4] = f2b(pf1.x); o0[5] = f2b(pf1.y); o0[6] = f2b(pf1.z); o0[7] = f2b(pf1.w);
    o1[0] = f2b(pf2.x); o1[1] = f2b(pf2.y); o1[2] = f2b(pf2.z); o1[3] = f2b(pf2.w);
    o1[4] = f2b(pf3.x); o1[5] = f2b(pf3.y); o1[6] = f2b(pf3.z); o1[7] = f2b(pf3.w);
    *(s16x8*)(Sb + r_st * 72 + c) = o0;
    *(s16x8*)(Sb + r_st * 72 + c + 8) = o1;
  };
  auto issue32 = [&](int kb) {
    const float* p = xrow + kb + (tid & 3) * 8;
    pf0 = *(const float4*)(p);
    pf1 = *(const float4*)(p + 4);
  };
  auto write32 = [&](short* Sb) {
    int c = (tid & 3) * 8;
    s16x8 o0;
    o0[0] = f2b(pf0.x); o0[1] = f2b(pf0.y); o0[2] = f2b(pf0.z); o0[3] = f2b(pf0.w);
    o0[4] = f2b(pf1.x); o0[5] = f2b(pf1.y); o0[6] = f2b(pf1.z); o0[7] = f2b(pf1.w);
    *(s16x8*)(Sb + r_st * 72 + c) = o0;
  };

  f32x4 accP[4][2], accT[4][2];
  zero_acc(accP); zero_acc(accT);

  // P1+P2 unified pipeline: 14 K=64 chunks over x cols [64t, 64t+64)
  // (chunks 0..5 -> pep/wpep, 6..12 -> tcr/wtcr, 13 -> K=32 tail).
  issue64(0); write64(R0);
  __syncthreads();
  for (int t = 0; t < 14; ++t) {
    short* cur = (t & 1) ? R1 : R0;
    short* nxt = (t & 1) ? R0 : R1;
    if (t < 13) { if (t == 12) issue32(832); else issue64(64 * (t + 1)); }
    if (t < 6) {
      mfma_step<2>(cur, 72, 0,  A.wpep, 384, 64 * t,      32 * w, l16, q, accP);
      mfma_step<2>(cur, 72, 32, A.wpep, 384, 64 * t + 32, 32 * w, l16, q, accP);
    } else if (t < 13) {
      mfma_step<2>(cur, 72, 0,  A.wtcr, 480, 64 * (t - 6),      32 * w, l16, q, accT);
      mfma_step<2>(cur, 72, 32, A.wtcr, 480, 64 * (t - 6) + 32, 32 * w, l16, q, accT);
    } else {
      mfma_step<2>(cur, 72, 0,  A.wtcr, 480, 448, 32 * w, l16, q, accT);
    }
    if (t < 13) { if (t == 12) write32(nxt); else write64(nxt); }
    __syncthreads();
  }
  epi_bias_store(accP, A.bpep, U, w, l16, q, false);   // U = pep
  epi_bias_store(accT, A.btcr, V, w, l16, q, false);   // V = tcr
  __syncthreads();

  // Attention (composited, seq_len=1): pa-pre = tcr @ Wcp^T, ta-pre = pep @ Wct^T.
  // Both GEMMs before either LN epilogue overwrites U/V.
  zero_acc(accP); zero_acc(accT);
#pragma unroll
  for (int kk = 0; kk < 4; ++kk)
    mfma_step<2>(V, 136, 32 * kk, A.wcp, 128, 32 * kk, 32 * w, l16, q, accP);
#pragma unroll
  for (int kk = 0; kk < 4; ++kk)
    mfma_step<2>(U, 136, 32 * kk, A.wct, 128, 32 * kk, 32 * w, l16, q, accT);
  epi_res_ln(accP, A.bcp, U, A.g1p, A.e1p, U, lnp, murs, w, l16, q, tid);
  epi_res_ln(accT, A.bct, V, A.g1t, A.e1t, V, lnp, murs, w, l16, q, tid);
  __syncthreads();   // murs reads done before FFN's H writes hit the overlay

  ffn_block(A.w1p, A.w2p, A.b1p, A.b2p, A.g2p, A.e2p, U, Hb, lnp, murs, w, l16, q, tid);
  ffn_block(A.w1t, A.w2t, A.b1t, A.b2t, A.g2t, A.e2t, V, Hb, lnp, murs, w, l16, q, tid);

  // P9: h1_pre = [pa|ta] @ w_h1^T + b_h1 ; BN1 partial stats ; store bf16
  zero_acc(accP);
#pragma unroll
  for (int s = 0; s < 8; ++s)
    mfma_step<2>((s < 4) ? U : V, 136, 32 * (s & 3), A.wh1, 256, 32 * s, 32 * w, l16, q, accP);
#pragma unroll
  for (int nt = 0; nt < 2; ++nt) {
    int col = 32 * w + 16 * nt + l16;
    float bb = A.bh1[col];
    float s = 0.f, sq = 0.f;
#pragma unroll
    for (int mt = 0; mt < 4; ++mt)
#pragma unroll
      for (int r = 0; r < 4; ++r) {
        float v = accP[mt][nt][r] + bb;
        s += v; sq += v * v;
        A.h1[(row0 + 16 * mt + 4 * q + r) * 128 + col] = f2b(v);
      }
    s += __shfl_xor(s, 16); sq += __shfl_xor(sq, 16);
    s += __shfl_xor(s, 32); sq += __shfl_xor(sq, 32);
    if (q == 0) {
      atomicAdd(&A.sum1[col], s);
      atomicAdd(&A.sq1[col], sq);
    }
  }
}

// ---------------------------------------------------------------------------
struct K2Args {
  const short* h1;
  const short* wh2;
  const float *bh2, *bn1g, *bn1b;
  const float *sum1, *sq1;
  float *sum2, *sq2;
  short* h2;
};

__global__ __launch_bounds__(256) void k2_main(K2Args A) {
  __shared__ __align__(16) short S2[64 * 136];
  __shared__ float s1[128], t1[128];
  const int tid = threadIdx.x;
  const int w = tid >> 6, lane = tid & 63, l16 = lane & 15, q = lane >> 4;
  const size_t row0 = (size_t)blockIdx.x * 64;

  if (tid < 128) {
    float su = A.sum1[tid], sq = A.sq1[tid];
    float mu = su * (1.0f / 65536.0f);
    float var = sq * (1.0f / 65536.0f) - mu * mu;
    float sc = A.bn1g[tid] * rsqrtf(var + 1e-5f);
    s1[tid] = sc;
    t1[tid] = A.bn1b[tid] - mu * sc;
  }
  __syncthreads();
  {
    int r = tid >> 2;
#pragma unroll
    for (int j = 0; j < 4; ++j) {
      int c = (tid & 3) * 32 + j * 8;
      s16x8 hv = *(const s16x8*)(A.h1 + (row0 + r) * 128 + c);
      s16x8 o;
#pragma unroll
      for (int i = 0; i < 8; ++i) {
        float f = b2f(hv[i]);
        f = gelu_f(f * s1[c + i] + t1[c + i]);
        o[i] = f2b(f);
      }
      *(s16x8*)(S2 + r * 136 + c) = o;
    }
  }
  __syncthreads();
  f32x4 acc[4][1];
  zero_acc(acc);
#pragma unroll
  for (int kk = 0; kk < 4; ++kk)
    mfma_step<1>(S2, 136, 32 * kk, A.wh2, 128, 32 * kk, 16 * w, l16, q, acc);
  int col = 16 * w + l16;
  float bb = A.bh2[col];
  float s = 0.f, sq = 0.f;
#pragma unroll
  for (int mt = 0; mt < 4; ++mt)
#pragma unroll
    for (int r = 0; r < 4; ++r) {
      float v = acc[mt][0][r] + bb;
      s += v; sq += v * v;
      A.h2[(row0 + 16 * mt + 4 * q + r) * 64 + col] = f2b(v);
    }
  s += __shfl_xor(s, 16); sq += __shfl_xor(sq, 16);
  s += __shfl_xor(s, 32); sq += __shfl_xor(sq, 32);
  if (q == 0) {
    atomicAdd(&A.sum2[col], s);
    atomicAdd(&A.sq2[col], sq);
  }
}

// ---------------------------------------------------------------------------
struct K3Args {
  const short* h2;
  const float *bn2g, *bn2b;
  const float *sum2, *sq2;
  const float *wout, *bout;
  float* out;
};

__global__ __launch_bounds__(256) void k3_main(K3Args A) {
  __shared__ float s2[64], t2[64], wo[64];
  const int tid = threadIdx.x;
  if (tid < 64) {
    float su = A.sum2[tid], sq = A.sq2[tid];
    float mu = su * (1.0f / 65536.0f);
    float var = sq * (1.0f / 65536.0f) - mu * mu;
    float sc = A.bn2g[tid] * rsqrtf(var + 1e-5f);
    s2[tid] = sc;
    t2[tid] = A.bn2b[tid] - mu * sc;
    wo[tid] = A.wout[tid];
  }
  __syncthreads();
  size_t row = (size_t)blockIdx.x * 32 + (tid >> 3);
  int c0 = (tid & 7) * 8;
  s16x8 hv = *(const s16x8*)(A.h2 + row * 64 + c0);
  float s = 0.f;
#pragma unroll
  for (int i = 0; i < 8; ++i) {
    float f = b2f(hv[i]);
    f = gelu_f(f * s2[c0 + i] + t2[c0 + i]);
    s += f * wo[c0 + i];
  }
  s += __shfl_xor(s, 1); s += __shfl_xor(s, 2); s += __shfl_xor(s, 4);
  if ((tid & 7) == 0) A.out[row] = s + A.bout[0];
}

// ---------------------------------------------------------------------------
struct CvtArgs {
  const float* src[8];
  short* dst;
  float* stats;
  // attention composite fusion inputs/outputs
  const float *wv[2], *wo[2], *bv[2], *bo[2];
  short* wc[2];
  float* bc[2];
};

// Blocks 0..403: fp32->bf16 convert (wv/wo regions skipped: the composite
// replaces them).  Blocks 404..435: Wc = wo@wv (bf16 out) and bc = wo@bv+bo.
__global__ __launch_bounds__(256) void k0_setup(CvtArgs A) {
  int b = blockIdx.x;
  const int tid = threadIdx.x;
  if (b >= 404) {
    int b2 = b - 404, pair = b2 >> 4, part = b2 & 15;
    const float* wv = A.wv[pair];
    const float* wo = A.wo[pair];
#pragma unroll
    for (int i = 0; i < 4; ++i) {
      int idx = part * 1024 + i * 256 + tid;
      int o = idx >> 7, k = idx & 127;
      const float* worow = wo + o * 128;
      float acc = 0.f;
#pragma unroll 4
      for (int j = 0; j < 128; ++j) acc += worow[j] * wv[j * 128 + k];
      A.wc[pair][idx] = f2b(acc);
    }
    if (part == 0 && tid < 128) {
      const float* bvp = A.bv[pair];
      float acc = A.bo[pair][tid];
      for (int j = 0; j < 128; ++j) acc += wo[tid * 128 + j] * bvp[j];
      A.bc[pair][tid] = acc;
    }
    return;
  }
  // segment starts in dst element coordinates (gap [110592,176128) skipped)
  const int st[8] = {0, 49152, 176128, 241664, 307200, 372736, 438272, 471040};
  if (b == 0) {
    A.stats[tid] = 0.0f;
    if (tid < 128) A.stats[256 + tid] = 0.0f;
  }
  int dstbase = b * 1024 + ((b >= 108) ? 65536 : 0);
  int seg = 0;
#pragma unroll
  for (int t = 1; t < 8; ++t) seg += (dstbase >= st[t]) ? 1 : 0;
  const float* s = A.src[seg];
  int loc = dstbase - st[seg] + tid * 4;
  float4 f = *(const float4*)(s + loc);
  int di = dstbase + tid * 4;
  A.dst[di + 0] = f2b(f.x);
  A.dst[di + 1] = f2b(f.y);
  A.dst[di + 2] = f2b(f.z);
  A.dst[di + 3] = f2b(f.w);
}

// ---------------------------------------------------------------------------
extern "C" void kernel_launch(void* const* d_in, const int* in_sizes, int n_in,
                              void* d_out, int out_size, void* d_ws, size_t ws_size,
                              hipStream_t stream) {
  (void)in_sizes; (void)n_in; (void)out_size; (void)ws_size;
  const float* x = (const float*)d_in[0];
  char* ws = (char*)d_ws;
  short* wb = (short*)ws;
  // bf16 weight segment offsets (elements). O_WCP/O_WCT hold the attention
  // composites; composite biases (fp32) live in the old wo_p2t region.
  enum { O_PEP = 0, O_TCR = 49152, O_WCP = 110592, O_BCF = 126976,
         O_WCT = 143360, O_W1P = 176128, O_W2P = 241664,
         O_W1T = 307200, O_W2T = 372736, O_H1 = 438272, O_H2 = 471040 };
  float* stats = (float*)(ws + 958464);           // 384 floats
  short* h1_pre = (short*)(ws + 960000);          // 65536*128 bf16
  short* h2_pre = (short*)(ws + 17737216);        // 65536*64 bf16
  float* bcomp = (float*)(ws + (size_t)O_BCF * 2);  // 256 floats

  CvtArgs ca;
  ca.src[0] = (const float*)d_in[1];   // w_pep
  ca.src[1] = (const float*)d_in[3];   // w_tcr
  ca.src[2] = (const float*)d_in[21];  // ffn_w1p
  ca.src[3] = (const float*)d_in[23];  // ffn_w2p
  ca.src[4] = (const float*)d_in[25];  // ffn_w1t
  ca.src[5] = (const float*)d_in[27];  // ffn_w2t
  ca.src[6] = (const float*)d_in[29];  // w_h1
  ca.src[7] = (const float*)d_in[33];  // w_h2
  ca.dst = wb;
  ca.stats = stats;
  ca.wv[0] = (const float*)d_in[5];   ca.bv[0] = (const float*)d_in[6];
  ca.wo[0] = (const float*)d_in[7];   ca.bo[0] = (const float*)d_in[8];
  ca.wv[1] = (const float*)d_in[9];   ca.bv[1] = (const float*)d_in[10];
  ca.wo[1] = (const float*)d_in[11];  ca.bo[1] = (const float*)d_in[12];
  ca.wc[0] = wb + O_WCP;  ca.wc[1] = wb + O_WCT;
  ca.bc[0] = bcomp;       ca.bc[1] = bcomp + 128;
  k0_setup<<<436, 256, 0, stream>>>(ca);

  K1Args a1;
  a1.x = x;
  a1.wpep = wb + O_PEP;  a1.wtcr = wb + O_TCR;
  a1.wcp = wb + O_WCP;   a1.wct = wb + O_WCT;
  a1.w1p = wb + O_W1P;   a1.w2p = wb + O_W2P;
  a1.w1t = wb + O_W1T;   a1.w2t = wb + O_W2T;
  a1.wh1 = wb + O_H1;
  a1.bpep = (const float*)d_in[2];
  a1.btcr = (const float*)d_in[4];
  a1.bcp = bcomp;
  a1.bct = bcomp + 128;
  a1.g1p = (const float*)d_in[13];  a1.e1p = (const float*)d_in[14];
  a1.g2p = (const float*)d_in[15];  a1.e2p = (const float*)d_in[16];
  a1.g1t = (const float*)d_in[17];  a1.e1t = (const float*)d_in[18];
  a1.g2t = (const float*)d_in[19];  a1.e2t = (const float*)d_in[20];
  a1.b1p = (const float*)d_in[22];
  a1.b2p = (const float*)d_in[24];
  a1.b1t = (const float*)d_in[26];
  a1.b2t = (const float*)d_in[28];
  a1.bh1 = (const float*)d_in[30];
  a1.sum1 = stats;
  a1.sq1 = stats + 128;
  a1.h1 = h1_pre;
  k1_main<<<1024, 256, 0, stream>>>(a1);

  K2Args a2;
  a2.h1 = h1_pre;
  a2.wh2 = wb + O_H2;
  a2.bh2 = (const float*)d_in[34];
  a2.bn1g = (const float*)d_in[31];
  a2.bn1b = (const float*)d_in[32];
  a2.sum1 = stats;
  a2.sq1 = stats + 128;
  a2.sum2 = stats + 256;
  a2.sq2 = stats + 320;
  a2.h2 = h2_pre;
  k2_main<<<1024, 256, 0, stream>>>(a2);

  K3Args a3;
  a3.h2 = h2_pre;
  a3.bn2g = (const float*)d_in[35];
  a3.bn2b = (const float*)d_in[36];
  a3.sum2 = stats + 256;
  a3.sq2 = stats + 320;
  a3.wout = (const float*)d_in[37];
  a3.bout = (const float*)d_in[38];
  a3.out = (float*)d_out;
  k3_main<<<2048, 256, 0, stream>>>(a3);
}

// Round 5
// 553.665 us; speedup vs baseline: 1.1046x; 1.0273x over previous
//
#include <hip/hip_runtime.h>
#include <hip/hip_bf16.h>
#include <math.h>

// ---------------------------------------------------------------------------
// CrossAttnMLP fused implementation for gfx950.
// K0 (weight fp32->bf16 + attention composite Wc=wo@wv + zero stats) ->
// K1 (fused transformer body -> h1_pre + BN1 partial stats) ->
// K2 (BN1 apply + gelu + h2 GEMM + BN2 stats) -> K3 (BN2 apply + gelu + dot).
//
// R5 changes (latency hiding; LDS/occupancy unchanged):
//  - P1P2: 2-deep register prefetch of x chunks (load t+2, write t+1) so HBM
//    latency spans two barrier intervals instead of being exposed in each
//  - FFN: 64-col H chunks double-buffered; W2(c) + W1(c+1) merged into one
//    barrier interval (two independent dep chains per interval)
//  - K0 composite: wv staged in LDS (kills stride-512B re-reads)
// ---------------------------------------------------------------------------

typedef __attribute__((ext_vector_type(8))) __bf16 bf16x8;
typedef __attribute__((ext_vector_type(8))) short s16x8;
typedef __attribute__((ext_vector_type(4))) float f32x4;

union S8U { s16x8 s; bf16x8 b; };

__device__ __forceinline__ short f2b(float f) {
  return __builtin_bit_cast(short, (__bf16)f);   // native RNE cvt on gfx950
}
__device__ __forceinline__ float b2f(short s) {
  union { unsigned u; float f; } v; v.u = ((unsigned)(unsigned short)s) << 16;
  return v.f;
}
// gelu(x) = x * sigmoid(2c(x+0.044715x^3)); max dev ~4e-4 vs erf-gelu.
__device__ __forceinline__ float gelu_f(float x) {
  float u = x * __builtin_fmaf(0.035677408136f, x * x, 0.7978845608028654f);
  float e = __expf(-2.0f * u);
  return x * __builtin_amdgcn_rcpf(1.0f + e);
}

// One K=32 MFMA step over a 64-row x (NTS*16)-col tile for one wave.
template<int NTS>
__device__ __forceinline__ void mfma_step(const short* __restrict__ Abuf, int lda, int kkA,
                                          const short* __restrict__ W, int ldw, int kw,
                                          int colbase, int l16, int q,
                                          f32x4 (&acc)[4][NTS]) {
  S8U a[4];
#pragma unroll
  for (int mt = 0; mt < 4; ++mt)
    a[mt].s = *(const s16x8*)(Abuf + (16 * mt + l16) * lda + kkA + 8 * q);
#pragma unroll
  for (int nt = 0; nt < NTS; ++nt) {
    S8U b;
    b.s = *(const s16x8*)(W + (size_t)(colbase + 16 * nt + l16) * ldw + kw + 8 * q);
#pragma unroll
    for (int mt = 0; mt < 4; ++mt)
      acc[mt][nt] = __builtin_amdgcn_mfma_f32_16x16x32_bf16(a[mt].b, b.b, acc[mt][nt], 0, 0, 0);
  }
}

template<int NTS>
__device__ __forceinline__ void zero_acc(f32x4 (&acc)[4][NTS]) {
  f32x4 z = {0.f, 0.f, 0.f, 0.f};
#pragma unroll
  for (int mt = 0; mt < 4; ++mt)
#pragma unroll
    for (int nt = 0; nt < NTS; ++nt) acc[mt][nt] = z;
}

__device__ __forceinline__ void epi_bias_store(f32x4 (&acc)[4][2], const float* __restrict__ bias,
                                               short* dst, int w, int l16, int q, bool do_gelu) {
#pragma unroll
  for (int nt = 0; nt < 2; ++nt) {
    int col = 32 * w + 16 * nt + l16;
    float bb = bias[col];
#pragma unroll
    for (int mt = 0; mt < 4; ++mt)
#pragma unroll
      for (int r = 0; r < 4; ++r) {
        int row = 16 * mt + 4 * q + r;
        float v = acc[mt][nt][r] + bb;
        if (do_gelu) v = gelu_f(v);
        dst[row * 136 + col] = f2b(v);
      }
  }
}

// Epilogue: acc += bias + residual(resbuf), LayerNorm over 128 cols, write dst.
__device__ __forceinline__ void epi_res_ln(f32x4 (&acc)[4][2], const float* __restrict__ bias,
                                           const short* resbuf,
                                           const float* __restrict__ g, const float* __restrict__ bta,
                                           short* dst, float (*lnp)[4][2], float (*murs)[2],
                                           int w, int l16, int q, int tid) {
#pragma unroll
  for (int nt = 0; nt < 2; ++nt) {
    int col = 32 * w + 16 * nt + l16;
    float bb = bias[col];
#pragma unroll
    for (int mt = 0; mt < 4; ++mt)
#pragma unroll
      for (int r = 0; r < 4; ++r) {
        int row = 16 * mt + 4 * q + r;
        acc[mt][nt][r] += bb + b2f(resbuf[row * 136 + col]);
      }
  }
#pragma unroll
  for (int mt = 0; mt < 4; ++mt) {
#pragma unroll
    for (int r = 0; r < 4; ++r) {
      float v0 = acc[mt][0][r], v1 = acc[mt][1][r];
      float s = v0 + v1;
      float sq = v0 * v0 + v1 * v1;
#pragma unroll
      for (int off = 1; off < 16; off <<= 1) {
        s += __shfl_xor(s, off);
        sq += __shfl_xor(sq, off);
      }
      if (l16 == 0) {
        int row = 16 * mt + 4 * q + r;
        lnp[row][w][0] = s;
        lnp[row][w][1] = sq;
      }
    }
  }
  __syncthreads();
  if (tid < 64) {
    float s = lnp[tid][0][0] + lnp[tid][1][0] + lnp[tid][2][0] + lnp[tid][3][0];
    float sq = lnp[tid][0][1] + lnp[tid][1][1] + lnp[tid][2][1] + lnp[tid][3][1];
    float mu = s * (1.0f / 128.0f);
    float var = sq * (1.0f / 128.0f) - mu * mu;
    murs[tid][0] = mu;
    murs[tid][1] = rsqrtf(var + 1e-5f);
  }
  __syncthreads();
#pragma unroll
  for (int nt = 0; nt < 2; ++nt) {
    int col = 32 * w + 16 * nt + l16;
    float gg = g[col], b2 = bta[col];
#pragma unroll
    for (int mt = 0; mt < 4; ++mt)
#pragma unroll
      for (int r = 0; r < 4; ++r) {
        int row = 16 * mt + 4 * q + r;
        float v = (acc[mt][nt][r] - murs[row][0]) * murs[row][1] * gg + b2;
        dst[row * 136 + col] = f2b(v);
      }
  }
}

// gelu+bias store of a 64x16-per-wave W1 chunk into H (stride 72).
__device__ __forceinline__ void store_h(short* H, f32x4 (&a)[4][1], const float* __restrict__ b1c,
                                        int w, int l16, int q) {
  int lcol = 16 * w + l16;
  float bb = b1c[lcol];
#pragma unroll
  for (int mt = 0; mt < 4; ++mt)
#pragma unroll
    for (int r = 0; r < 4; ++r)
      H[(16 * mt + 4 * q + r) * 72 + lcol] = f2b(gelu_f(a[mt][0][r] + bb));
}

// FFN block: act = LN(act + W2 @ gelu(W1 @ act + b1) + b2).
// 64-col H chunks, double-buffered (H0/H1): interval c runs W2(c) from
// H[c&1] AND W1(c+1) into H[(c+1)&1] -- two independent chains per barrier.
__device__ __forceinline__ void ffn_block(const short* __restrict__ w1, const short* __restrict__ w2,
                                          const float* __restrict__ b1, const float* __restrict__ b2,
                                          const float* __restrict__ g, const float* __restrict__ bta,
                                          short* act, short* H0, short* H1,
                                          float (*lnp)[4][2], float (*murs)[2],
                                          int w, int l16, int q, int tid) {
  f32x4 acc2[4][2];
  zero_acc(acc2);
  {
    f32x4 acch[4][1];
    zero_acc(acch);
#pragma unroll
    for (int kk = 0; kk < 4; ++kk)
      mfma_step<1>(act, 136, 32 * kk, w1, 128, 32 * kk, 16 * w, l16, q, acch);
    store_h(H0, acch, b1, w, l16, q);
  }
  __syncthreads();
#pragma unroll
  for (int c = 0; c < 8; ++c) {
    short* Hr = (c & 1) ? H1 : H0;
    short* Hw = (c & 1) ? H0 : H1;
    f32x4 accn[4][1];
    if (c < 7) {
      zero_acc(accn);
#pragma unroll
      for (int kk = 0; kk < 4; ++kk)
        mfma_step<1>(act, 136, 32 * kk, w1, 128, 32 * kk, (c + 1) * 64 + 16 * w, l16, q, accn);
    }
#pragma unroll
    for (int kk = 0; kk < 2; ++kk)
      mfma_step<2>(Hr, 72, 32 * kk, w2, 512, c * 64 + 32 * kk, 32 * w, l16, q, acc2);
    if (c < 7) store_h(Hw, accn, b1 + (c + 1) * 64, w, l16, q);
    __syncthreads();
  }
  epi_res_ln(acc2, b2, act, g, bta, act, lnp, murs, w, l16, q, tid);
  __syncthreads();   // protect lnp/murs (inside H region) from next H writes
}

// ---------------------------------------------------------------------------
struct K1Args {
  const float* x;
  const short *wpep, *wtcr, *wcp, *wct, *w1p, *w2p, *w1t, *w2t, *wh1;
  const float *bpep, *btcr, *bcp, *bct;
  const float *g1p, *e1p, *g2p, *e2p, *g1t, *e1t, *g2t, *e2t;
  const float *b1p, *b2p, *b1t, *b2t, *bh1;
  float *sum1, *sq1;
  short* h1;
};

__global__ __launch_bounds__(256, 3) void k1_main(K1Args A) {
  // LDS: U,V 64x136 bf16; R = 2x(64x72) staging dbuf, overlaid with FFN
  // H0/H1 (64x72 each) and LN scratch (last 2560 B). 53248 B -> 3 blocks/CU.
  __shared__ __align__(16) short smem[2 * 64 * 136 + 2 * 64 * 72];
  short* U = smem;
  short* V = U + 64 * 136;
  short* Rst = V + 64 * 136;
  short* R0 = Rst;
  short* R1 = Rst + 64 * 72;
  float (*lnp)[4][2] = (float (*)[4][2])(void*)(Rst + 7936);   // 2048 B
  float (*murs)[2] = (float (*)[2])(void*)(Rst + 8960);        // 512 B

  const int tid = threadIdx.x;
  const int w = tid >> 6;
  const int lane = tid & 63;
  const int l16 = lane & 15;
  const int q = lane >> 4;
  const size_t row0 = (size_t)blockIdx.x * 64;

  const int r_st = tid >> 2;
  const float* xrow = A.x + (row0 + r_st) * 864;

  float4 pA[4], pB[4];
  auto ld64 = [&](int kb, float4 (&pf)[4]) {
    const float* p = xrow + kb + (tid & 3) * 16;
    pf[0] = *(const float4*)(p);
    pf[1] = *(const float4*)(p + 4);
    pf[2] = *(const float4*)(p + 8);
    pf[3] = *(const float4*)(p + 12);
  };
  auto ld32 = [&](int kb, float4 (&pf)[4]) {
    const float* p = xrow + kb + (tid & 3) * 8;
    pf[0] = *(const float4*)(p);
    pf[1] = *(const float4*)(p + 4);
  };
  auto st64 = [&](short* Sb, float4 (&pf)[4]) {
    int c = (tid & 3) * 16;
    s16x8 o0, o1;
    o0[0] = f2b(pf[0].x); o0[1] = f2b(pf[0].y); o0[2] = f2b(pf[0].z); o0[3] = f2b(pf[0].w);
    o0[4] = f2b(pf[1].x); o0[5] = f2b(pf[1].y); o0[6] = f2b(pf[1].z); o0[7] = f2b(pf[1].w);
    o1[0] = f2b(pf[2].x); o1[1] = f2b(pf[2].y); o1[2] = f2b(pf[2].z); o1[3] = f2b(pf[2].w);
    o1[4] = f2b(pf[3].x); o1[5] = f2b(pf[3].y); o1[6] = f2b(pf[3].z); o1[7] = f2b(pf[3].w);
    *(s16x8*)(Sb + r_st * 72 + c) = o0;
    *(s16x8*)(Sb + r_st * 72 + c + 8) = o1;
  };
  auto st32 = [&](short* Sb, float4 (&pf)[4]) {
    int c = (tid & 3) * 8;
    s16x8 o0;
    o0[0] = f2b(pf[0].x); o0[1] = f2b(pf[0].y); o0[2] = f2b(pf[0].z); o0[3] = f2b(pf[0].w);
    o0[4] = f2b(pf[1].x); o0[5] = f2b(pf[1].y); o0[6] = f2b(pf[1].z); o0[7] = f2b(pf[1].w);
    *(s16x8*)(Sb + r_st * 72 + c) = o0;
  };

  f32x4 accP[4][2], accT[4][2];
  zero_acc(accP); zero_acc(accT);

  // P1+P2: 14 K-chunks of x (0..12 are 64 wide, 13 is the 32-wide tail).
  // 2-deep register prefetch: at interval t, issue load of chunk t+2, run
  // MFMAs on chunk t (LDS), convert+write chunk t+1 (regs loaded at t-1).
  ld64(0, pA);
  ld64(64, pB);
  st64(R0, pA);
  __syncthreads();
#pragma unroll
  for (int t = 0; t < 14; ++t) {
    if (t + 2 < 13) {
      if (t & 1) ld64(64 * (t + 2), pB); else ld64(64 * (t + 2), pA);
    } else if (t + 2 == 13) {
      if (t & 1) ld32(832, pB); else ld32(832, pA);
    }
    short* cur = (t & 1) ? R1 : R0;
    short* nxt = (t & 1) ? R0 : R1;
    if (t < 6) {
      mfma_step<2>(cur, 72, 0,  A.wpep, 384, 64 * t,      32 * w, l16, q, accP);
      mfma_step<2>(cur, 72, 32, A.wpep, 384, 64 * t + 32, 32 * w, l16, q, accP);
    } else if (t < 13) {
      mfma_step<2>(cur, 72, 0,  A.wtcr, 480, 64 * (t - 6),      32 * w, l16, q, accT);
      mfma_step<2>(cur, 72, 32, A.wtcr, 480, 64 * (t - 6) + 32, 32 * w, l16, q, accT);
    } else {
      mfma_step<2>(cur, 72, 0,  A.wtcr, 480, 448, 32 * w, l16, q, accT);
    }
    if (t + 1 < 13) {
      if (t & 1) st64(nxt, pA); else st64(nxt, pB);
    } else if (t + 1 == 13) {
      if (t & 1) st32(nxt, pA); else st32(nxt, pB);
    }
    __syncthreads();
  }
  epi_bias_store(accP, A.bpep, U, w, l16, q, false);   // U = pep
  epi_bias_store(accT, A.btcr, V, w, l16, q, false);   // V = tcr
  __syncthreads();

  // Attention (composited, seq_len=1): pa-pre = tcr @ Wcp^T, ta-pre = pep @ Wct^T.
  zero_acc(accP); zero_acc(accT);
#pragma unroll
  for (int kk = 0; kk < 4; ++kk)
    mfma_step<2>(V, 136, 32 * kk, A.wcp, 128, 32 * kk, 32 * w, l16, q, accP);
#pragma unroll
  for (int kk = 0; kk < 4; ++kk)
    mfma_step<2>(U, 136, 32 * kk, A.wct, 128, 32 * kk, 32 * w, l16, q, accT);
  epi_res_ln(accP, A.bcp, U, A.g1p, A.e1p, U, lnp, murs, w, l16, q, tid);
  epi_res_ln(accT, A.bct, V, A.g1t, A.e1t, V, lnp, murs, w, l16, q, tid);
  __syncthreads();   // murs reads done before FFN's H writes hit the overlay

  ffn_block(A.w1p, A.w2p, A.b1p, A.b2p, A.g2p, A.e2p, U, R0, R1, lnp, murs, w, l16, q, tid);
  ffn_block(A.w1t, A.w2t, A.b1t, A.b2t, A.g2t, A.e2t, V, R0, R1, lnp, murs, w, l16, q, tid);

  // P9: h1_pre = [pa|ta] @ w_h1^T + b_h1 ; BN1 partial stats ; store bf16
  zero_acc(accP);
#pragma unroll
  for (int s = 0; s < 8; ++s)
    mfma_step<2>((s < 4) ? U : V, 136, 32 * (s & 3), A.wh1, 256, 32 * s, 32 * w, l16, q, accP);
#pragma unroll
  for (int nt = 0; nt < 2; ++nt) {
    int col = 32 * w + 16 * nt + l16;
    float bb = A.bh1[col];
    float s = 0.f, sq = 0.f;
#pragma unroll
    for (int mt = 0; mt < 4; ++mt)
#pragma unroll
      for (int r = 0; r < 4; ++r) {
        float v = accP[mt][nt][r] + bb;
        s += v; sq += v * v;
        A.h1[(row0 + 16 * mt + 4 * q + r) * 128 + col] = f2b(v);
      }
    s += __shfl_xor(s, 16); sq += __shfl_xor(sq, 16);
    s += __shfl_xor(s, 32); sq += __shfl_xor(sq, 32);
    if (q == 0) {
      atomicAdd(&A.sum1[col], s);
      atomicAdd(&A.sq1[col], sq);
    }
  }
}

// ---------------------------------------------------------------------------
struct K2Args {
  const short* h1;
  const short* wh2;
  const float *bh2, *bn1g, *bn1b;
  const float *sum1, *sq1;
  float *sum2, *sq2;
  short* h2;
};

__global__ __launch_bounds__(256) void k2_main(K2Args A) {
  __shared__ __align__(16) short S2[64 * 136];
  __shared__ float s1[128], t1[128];
  const int tid = threadIdx.x;
  const int w = tid >> 6, lane = tid & 63, l16 = lane & 15, q = lane >> 4;
  const size_t row0 = (size_t)blockIdx.x * 64;

  if (tid < 128) {
    float su = A.sum1[tid], sq = A.sq1[tid];
    float mu = su * (1.0f / 65536.0f);
    float var = sq * (1.0f / 65536.0f) - mu * mu;
    float sc = A.bn1g[tid] * rsqrtf(var + 1e-5f);
    s1[tid] = sc;
    t1[tid] = A.bn1b[tid] - mu * sc;
  }
  __syncthreads();
  {
    int r = tid >> 2;
#pragma unroll
    for (int j = 0; j < 4; ++j) {
      int c = (tid & 3) * 32 + j * 8;
      s16x8 hv = *(const s16x8*)(A.h1 + (row0 + r) * 128 + c);
      s16x8 o;
#pragma unroll
      for (int i = 0; i < 8; ++i) {
        float f = b2f(hv[i]);
        f = gelu_f(f * s1[c + i] + t1[c + i]);
        o[i] = f2b(f);
      }
      *(s16x8*)(S2 + r * 136 + c) = o;
    }
  }
  __syncthreads();
  f32x4 acc[4][1];
  zero_acc(acc);
#pragma unroll
  for (int kk = 0; kk < 4; ++kk)
    mfma_step<1>(S2, 136, 32 * kk, A.wh2, 128, 32 * kk, 16 * w, l16, q, acc);
  int col = 16 * w + l16;
  float bb = A.bh2[col];
  float s = 0.f, sq = 0.f;
#pragma unroll
  for (int mt = 0; mt < 4; ++mt)
#pragma unroll
    for (int r = 0; r < 4; ++r) {
      float v = acc[mt][0][r] + bb;
      s += v; sq += v * v;
      A.h2[(row0 + 16 * mt + 4 * q + r) * 64 + col] = f2b(v);
    }
  s += __shfl_xor(s, 16); sq += __shfl_xor(sq, 16);
  s += __shfl_xor(s, 32); sq += __shfl_xor(sq, 32);
  if (q == 0) {
    atomicAdd(&A.sum2[col], s);
    atomicAdd(&A.sq2[col], sq);
  }
}

// ---------------------------------------------------------------------------
struct K3Args {
  const short* h2;
  const float *bn2g, *bn2b;
  const float *sum2, *sq2;
  const float *wout, *bout;
  float* out;
};

__global__ __launch_bounds__(256) void k3_main(K3Args A) {
  __shared__ float s2[64], t2[64], wo[64];
  const int tid = threadIdx.x;
  if (tid < 64) {
    float su = A.sum2[tid], sq = A.sq2[tid];
    float mu = su * (1.0f / 65536.0f);
    float var = sq * (1.0f / 65536.0f) - mu * mu;
    float sc = A.bn2g[tid] * rsqrtf(var + 1e-5f);
    s2[tid] = sc;
    t2[tid] = A.bn2b[tid] - mu * sc;
    wo[tid] = A.wout[tid];
  }
  __syncthreads();
  size_t row = (size_t)blockIdx.x * 32 + (tid >> 3);
  int c0 = (tid & 7) * 8;
  s16x8 hv = *(const s16x8*)(A.h2 + row * 64 + c0);
  float s = 0.f;
#pragma unroll
  for (int i = 0; i < 8; ++i) {
    float f = b2f(hv[i]);
    f = gelu_f(f * s2[c0 + i] + t2[c0 + i]);
    s += f * wo[c0 + i];
  }
  s += __shfl_xor(s, 1); s += __shfl_xor(s, 2); s += __shfl_xor(s, 4);
  if ((tid & 7) == 0) A.out[row] = s + A.bout[0];
}

// ---------------------------------------------------------------------------
struct CvtArgs {
  const float* src[8];
  short* dst;
  float* stats;
  // attention composite fusion inputs/outputs
  const float *wv[2], *wo[2], *bv[2], *bo[2];
  short* wc[2];
  float* bc[2];
};

// Blocks 0..403: fp32->bf16 convert (wv/wo regions skipped: the composite
// replaces them).  Blocks 404..435: Wc = wo@wv (bf16 out) and bc = wo@bv+bo,
// with wv staged in LDS (row-major) to avoid stride-512B global re-reads.
__global__ __launch_bounds__(256) void k0_setup(CvtArgs A) {
  __shared__ float wvs[128 * 128];
  int b = blockIdx.x;
  const int tid = threadIdx.x;
  if (b >= 404) {
    int b2 = b - 404, pair = b2 >> 4, part = b2 & 15;
    const float* wv = A.wv[pair];
    const float* wo = A.wo[pair];
#pragma unroll
    for (int i = 0; i < 16; ++i) {
      int idx4 = (i * 256 + tid) * 4;
      *(float4*)(wvs + idx4) = *(const float4*)(wv + idx4);
    }
    __syncthreads();
#pragma unroll
    for (int i = 0; i < 4; ++i) {
      int idx = part * 1024 + i * 256 + tid;
      int o = idx >> 7, k = idx & 127;
      const float* worow = wo + o * 128;
      float acc = 0.f;
#pragma unroll 4
      for (int j = 0; j < 128; ++j) acc += worow[j] * wvs[j * 128 + k];
      A.wc[pair][idx] = f2b(acc);
    }
    if (part == 0 && tid < 128) {
      const float* bvp = A.bv[pair];
      float acc = A.bo[pair][tid];
      for (int j = 0; j < 128; ++j) acc += wo[tid * 128 + j] * bvp[j];
      A.bc[pair][tid] = acc;
    }
    return;
  }
  // segment starts in dst element coordinates (gap [110592,176128) skipped)
  const int st[8] = {0, 49152, 176128, 241664, 307200, 372736, 438272, 471040};
  if (b == 0) {
    A.stats[tid] = 0.0f;
    if (tid < 128) A.stats[256 + tid] = 0.0f;
  }
  int dstbase = b * 1024 + ((b >= 108) ? 65536 : 0);
  int seg = 0;
#pragma unroll
  for (int t = 1; t < 8; ++t) seg += (dstbase >= st[t]) ? 1 : 0;
  const float* s = A.src[seg];
  int loc = dstbase - st[seg] + tid * 4;
  float4 f = *(const float4*)(s + loc);
  int di = dstbase + tid * 4;
  A.dst[di + 0] = f2b(f.x);
  A.dst[di + 1] = f2b(f.y);
  A.dst[di + 2] = f2b(f.z);
  A.dst[di + 3] = f2b(f.w);
}

// ---------------------------------------------------------------------------
extern "C" void kernel_launch(void* const* d_in, const int* in_sizes, int n_in,
                              void* d_out, int out_size, void* d_ws, size_t ws_size,
                              hipStream_t stream) {
  (void)in_sizes; (void)n_in; (void)out_size; (void)ws_size;
  const float* x = (const float*)d_in[0];
  char* ws = (char*)d_ws;
  short* wb = (short*)ws;
  // bf16 weight segment offsets (elements). O_WCP/O_WCT hold the attention
  // composites; composite biases (fp32) live in the old wo_p2t region.
  enum { O_PEP = 0, O_TCR = 49152, O_WCP = 110592, O_BCF = 126976,
         O_WCT = 143360, O_W1P = 176128, O_W2P = 241664,
         O_W1T = 307200, O_W2T = 372736, O_H1 = 438272, O_H2 = 471040 };
  float* stats = (float*)(ws + 958464);           // 384 floats
  short* h1_pre = (short*)(ws + 960000);          // 65536*128 bf16
  short* h2_pre = (short*)(ws + 17737216);        // 65536*64 bf16
  float* bcomp = (float*)(ws + (size_t)O_BCF * 2);  // 256 floats

  CvtArgs ca;
  ca.src[0] = (const float*)d_in[1];   // w_pep
  ca.src[1] = (const float*)d_in[3];   // w_tcr
  ca.src[2] = (const float*)d_in[21];  // ffn_w1p
  ca.src[3] = (const float*)d_in[23];  // ffn_w2p
  ca.src[4] = (const float*)d_in[25];  // ffn_w1t
  ca.src[5] = (const float*)d_in[27];  // ffn_w2t
  ca.src[6] = (const float*)d_in[29];  // w_h1
  ca.src[7] = (const float*)d_in[33];  // w_h2
  ca.dst = wb;
  ca.stats = stats;
  ca.wv[0] = (const float*)d_in[5];   ca.bv[0] = (const float*)d_in[6];
  ca.wo[0] = (const float*)d_in[7];   ca.bo[0] = (const float*)d_in[8];
  ca.wv[1] = (const float*)d_in[9];   ca.bv[1] = (const float*)d_in[10];
  ca.wo[1] = (const float*)d_in[11];  ca.bo[1] = (const float*)d_in[12];
  ca.wc[0] = wb + O_WCP;  ca.wc[1] = wb + O_WCT;
  ca.bc[0] = bcomp;       ca.bc[1] = bcomp + 128;
  k0_setup<<<436, 256, 0, stream>>>(ca);

  K1Args a1;
  a1.x = x;
  a1.wpep = wb + O_PEP;  a1.wtcr = wb + O_TCR;
  a1.wcp = wb + O_WCP;   a1.wct = wb + O_WCT;
  a1.w1p = wb + O_W1P;   a1.w2p = wb + O_W2P;
  a1.w1t = wb + O_W1T;   a1.w2t = wb + O_W2T;
  a1.wh1 = wb + O_H1;
  a1.bpep = (const float*)d_in[2];
  a1.btcr = (const float*)d_in[4];
  a1.bcp = bcomp;
  a1.bct = bcomp + 128;
  a1.g1p = (const float*)d_in[13];  a1.e1p = (const float*)d_in[14];
  a1.g2p = (const float*)d_in[15];  a1.e2p = (const float*)d_in[16];
  a1.g1t = (const float*)d_in[17];  a1.e1t = (const float*)d_in[18];
  a1.g2t = (const float*)d_in[19];  a1.e2t = (const float*)d_in[20];
  a1.b1p = (const float*)d_in[22];
  a1.b2p = (const float*)d_in[24];
  a1.b1t = (const float*)d_in[26];
  a1.b2t = (const float*)d_in[28];
  a1.bh1 = (const float*)d_in[30];
  a1.sum1 = stats;
  a1.sq1 = stats + 128;
  a1.h1 = h1_pre;
  k1_main<<<1024, 256, 0, stream>>>(a1);

  K2Args a2;
  a2.h1 = h1_pre;
  a2.wh2 = wb + O_H2;
  a2.bh2 = (const float*)d_in[34];
  a2.bn1g = (const float*)d_in[31];
  a2.bn1b = (const float*)d_in[32];
  a2.sum1 = stats;
  a2.sq1 = stats + 128;
  a2.sum2 = stats + 256;
  a2.sq2 = stats + 320;
  a2.h2 = h2_pre;
  k2_main<<<1024, 256, 0, stream>>>(a2);

  K3Args a3;
  a3.h2 = h2_pre;
  a3.bn2g = (const float*)d_in[35];
  a3.bn2b = (const float*)d_in[36];
  a3.sum2 = stats + 256;
  a3.sq2 = stats + 320;
  a3.wout = (const float*)d_in[37];
  a3.bout = (const float*)d_in[38];
  a3.out = (float*)d_out;
  k3_main<<<2048, 256, 0, stream>>>(a3);
}